// Round 2
// baseline (253.546 us; speedup 1.0000x reference)
//
#include <hip/hip_runtime.h>

typedef unsigned short u16;
typedef unsigned int u32;
typedef __attribute__((ext_vector_type(8))) short short8;
typedef __attribute__((ext_vector_type(4))) float f32x4;

#define DEV static __device__ __forceinline__

DEV float bf2f(u16 u){ u32 i = ((u32)u)<<16; float f; __builtin_memcpy(&f,&i,4); return f; }
DEV u16 f2bf(float f){ u32 i; __builtin_memcpy(&i,&f,4); u32 r = i + 0x7FFFu + ((i>>16)&1u); return (u16)(r>>16); }

DEV void gld16(const void* gp, void* lp){
  __builtin_amdgcn_global_load_lds((const __attribute__((address_space(1))) void*)gp,
                                   (__attribute__((address_space(3))) void*)lp, 16, 0, 0);
}

// ---------------- utility kernels ----------------

__global__ void k_cvt_x(const float* __restrict__ x, u16* __restrict__ xb){
  size_t base = ((size_t)blockIdx.x*256 + threadIdx.x)*4;
  float4 v = *(const float4*)(x + base);
  ushort4 o; o.x=f2bf(v.x); o.y=f2bf(v.y); o.z=f2bf(v.z); o.w=f2bf(v.w);
  *(ushort4*)(xb + base) = o;
}

// src: K x N fp32 row-major  ->  dst: N x K bf16 row-major
__global__ void k_wtrans(const float* __restrict__ src, u16* __restrict__ dst, int N, int K){
  __shared__ float tile[32][33];
  int n0 = blockIdx.x*32, k0 = blockIdx.y*32;
  int tx = threadIdx.x, ty = threadIdx.y;
  #pragma unroll
  for (int i=0;i<4;++i)
    tile[ty + i*8][tx] = src[(size_t)(k0 + ty + i*8)*N + n0 + tx];
  __syncthreads();
  #pragma unroll
  for (int i=0;i<4;++i)
    dst[(size_t)(n0 + ty + i*8)*K + k0 + tx] = f2bf(tile[tx][ty + i*8]);
}

// Vraw [4096][1536] bf16 -> VbT [(bh)*256+v][2048] bf16
__global__ void k_vtrans(const u16* __restrict__ Vraw, u16* __restrict__ VbT){
  __shared__ u16 tile[32][33];
  int bh = blockIdx.z, b = bh/6, h = bh%6;
  int t0 = blockIdx.x*32, v0 = blockIdx.y*32;
  int tx = threadIdx.x, ty = threadIdx.y;
  #pragma unroll
  for (int i=0;i<4;++i)
    tile[ty+i*8][tx] = Vraw[(size_t)(b*2048 + t0 + ty + i*8)*1536 + h*256 + v0 + tx];
  __syncthreads();
  #pragma unroll
  for (int i=0;i<4;++i)
    VbT[(size_t)(bh*256 + v0 + ty + i*8)*2048 + t0 + tx] = tile[tx][ty+i*8];
}

// xPos rotary, in place on [4096][768] bf16 (cols = h*128 + d)
__global__ void k_xpos(u16* __restrict__ P, float sign){
  int idx = blockIdx.x*256 + threadIdx.x;   // (m*6 + h)*64 + j
  int j  = idx & 63;
  int mh = idx >> 6;
  int h  = mh % 6;
  int m  = mh / 6;
  int t  = m & 2047;
  float inv_freq = expf(-(float)j * (9.210340371976184f/64.f)); // 10000^(-j/64)
  float angle = (float)t * inv_freq;
  float zeta = (float)(j + 64) * (1.f/128.f);
  float dec = exp2f(log2f(zeta) * (sign*(float)t*(1.f/512.f)));
  float sn, cs;
  sincosf(angle, &sn, &cs);
  cs *= dec; sn *= dec;
  size_t base = (size_t)m*768 + h*128 + j;
  float x1 = bf2f(P[base]), x2 = bf2f(P[base+64]);
  P[base]    = f2bf(x1*cs - x2*sn);
  P[base+64] = f2bf(x1*sn + x2*cs);
}

// ---------------- GEMM: C[M,N] = A[M,K] * BT[N,K]^T  (bf16 in, fp32 acc) ----------------
// MODE 0: fused QKVG epilogue (bf16 outs, silu on G region). MODE 1: fp32 out.
// BM: 64 or 128 row-tile. BN fixed 128.
template<int MODE, int BM>
__global__ __launch_bounds__(256)
void k_gemm(const u16* __restrict__ A, const u16* __restrict__ BT,
            int K, int N,
            u16* __restrict__ Qr, u16* __restrict__ Kr,
            u16* __restrict__ Vraw, u16* __restrict__ Gb,
            float* __restrict__ Out)
{
  constexpr int MR = BM/32;          // acc rows per wave
  __shared__ u16 As[BM*64];
  __shared__ u16 Bs[128*64];
  const int tid = threadIdx.x;
  const int w = tid>>6, l = tid&63, g = l>>4, ln = l&15;
  const int wr = w>>1, wc = w&1;
  const int m0 = blockIdx.x*BM, n0 = blockIdx.y*128;
  const f32x4 fz = {0.f,0.f,0.f,0.f};
  f32x4 acc[MR][4];
  #pragma unroll
  for (int m=0;m<MR;++m)
    #pragma unroll
    for (int n=0;n<4;++n) acc[m][n] = fz;

  const int nk = K>>6;
  for (int kt=0; kt<nk; ++kt){
    const int k0 = kt<<6;
    #pragma unroll
    for (int i=0;i<BM/32;++i){
      int off = i*4096 + tid*16;
      int row = off>>7;                       // 128B per row
      int colb = (((off>>4)&7)<<4) ^ ((row&7)<<4);
      gld16(A  + (size_t)(m0+row)*K + k0 + (colb>>1), (char*)As + i*4096 + w*1024);
    }
    #pragma unroll
    for (int i=0;i<4;++i){
      int off = i*4096 + tid*16;
      int row = off>>7;
      int colb = (((off>>4)&7)<<4) ^ ((row&7)<<4);
      gld16(BT + (size_t)(n0+row)*K + k0 + (colb>>1), (char*)Bs + i*4096 + w*1024);
    }
    __syncthreads();
    #pragma unroll
    for (int kk=0;kk<2;++kk){
      short8 a[MR], b[4];
      #pragma unroll
      for (int m=0;m<MR;++m){
        int row = wr*(BM/2) + m*16 + ln;
        int byte = row*128 + ((kk*64 + g*16) ^ ((row&7)<<4));
        a[m] = *(const short8*)((const char*)As + byte);
      }
      #pragma unroll
      for (int n=0;n<4;++n){
        int row = wc*64 + n*16 + ln;
        int byte = row*128 + ((kk*64 + g*16) ^ ((row&7)<<4));
        b[n] = *(const short8*)((const char*)Bs + byte);
      }
      #pragma unroll
      for (int m=0;m<MR;++m)
        #pragma unroll
        for (int n=0;n<4;++n)
          acc[m][n] = __builtin_amdgcn_mfma_f32_16x16x32_bf16(a[m], b[n], acc[m][n], 0,0,0);
    }
    __syncthreads();
  }
  // epilogue
  const int region = n0/768;  // tile never crosses a 768 boundary
  #pragma unroll
  for (int m=0;m<MR;++m){
    int grow0 = m0 + wr*(BM/2) + m*16 + g*4;
    #pragma unroll
    for (int n=0;n<4;++n){
      int c = n0 + wc*64 + n*16 + ln;
      #pragma unroll
      for (int r=0;r<4;++r){
        float v = acc[m][n][r];
        size_t grow = (size_t)(grow0 + r);
        if (MODE == 1){
          Out[grow*(size_t)N + c] = v;
        } else {
          if (region==0)      Qr[grow*768 + c] = f2bf(v);
          else if (region==1) Kr[grow*768 + (c-768)] = f2bf(v);
          else if (region<4)  Vraw[grow*1536 + (c-1536)] = f2bf(v);
          else { float sg = v/(1.f+__expf(-v)); Gb[grow*1536 + (c-3072)] = f2bf(sg); }
        }
      }
    }
  }
}

// ---------------- retention (flash-style, causal decay, key-split) ----------------
// grid (80, 12): blockIdx.x -> (qb, seg) work item, blockIdx.y -> bh.
// Each block: 16 q-rows per wave x 64 q-rows, processes <=8 key-blocks, atomically
// accumulates its (pre-normalized) partial O into Of (zeroed beforehand).
__global__ __launch_bounds__(256)
void k_ret(const u16* __restrict__ Qb, const u16* __restrict__ Kb,
           const u16* __restrict__ VbT, float* __restrict__ Of)
{
  __shared__ u16 Ks[64*128];    // 16 KB, swizzled
  __shared__ u16 Vt[256*64];    // 32 KB, V^T tile [v][key], swizzled
  __shared__ float Ps[64*64];   // 16 KB, swizzled
  const int tid = threadIdx.x, w = tid>>6, l = tid&63, g = l>>4, ln = l&15;
  // decode (qb, seg) from blockIdx.x in [0,80)
  int i = blockIdx.x, qb, s;
  if (i < 8)       { qb = i; s = 0; }
  else if (i < 24) { int j = i-8;  qb = 8  + (j>>1); s = j&1; }
  else if (i < 48) { int j = i-24; int q3 = j/3; qb = 16 + q3; s = j - q3*3; }
  else             { int j = i-48; qb = 24 + (j>>2); s = j&3; }
  const int bh = blockIdx.y, b = bh/6, h = bh%6;
  const float omg = exp2f(-(float)(5+h));   // 1-gamma (exact)
  const float gamma = 1.f - omg;
  const float lg2g = log2f(gamma);
  const float scale = 0.08838834764831845f; // 128^-0.5
  const int q0 = qb*64;
  const f32x4 fz = {0.f,0.f,0.f,0.f};

  short8 aq[4];
  {
    const size_t qrow = (size_t)(b*2048 + q0 + w*16 + ln)*768 + h*128;
    #pragma unroll
    for (int kk=0;kk<4;++kk) aq[kk] = *(const short8*)(Qb + qrow + kk*32 + g*8);
  }
  f32x4 accO[16];
  #pragma unroll
  for (int i2=0;i2<16;++i2) accO[i2] = fz;

  const int kb0 = s*8;
  const int kb1 = min(kb0+7, qb);
  for (int kb=kb0; kb<=kb1; ++kb){
    #pragma unroll
    for (int i2=0;i2<4;++i2){   // K tile: 64 rows x 128 d
      int off = i2*4096 + tid*16;
      int row = off>>8;      // 256B rows
      int colb = (((off>>4)&15)<<4) ^ ((row&7)<<4);
      gld16(Kb + (size_t)(b*2048 + kb*64 + row)*768 + h*128 + (colb>>1),
            (char*)Ks + i2*4096 + w*1024);
    }
    #pragma unroll
    for (int i2=0;i2<8;++i2){   // V^T tile: 256 rows(v) x 64 keys
      int off = i2*4096 + tid*16;
      int row = off>>7;      // 128B rows
      int colb = (((off>>4)&7)<<4) ^ ((row&7)<<4);
      gld16(VbT + (size_t)(bh*256 + row)*2048 + kb*64 + (colb>>1),
            (char*)Vt + i2*4096 + w*1024);
    }
    __syncthreads();

    // S = Q K^T (wave's 16 q-rows x 64 keys)
    f32x4 sacc[4]; sacc[0]=fz; sacc[1]=fz; sacc[2]=fz; sacc[3]=fz;
    #pragma unroll
    for (int kk=0;kk<4;++kk){
      #pragma unroll
      for (int n=0;n<4;++n){
        int row = n*16 + ln;
        int byte = row*256 + ((kk*64 + g*16) ^ ((row&7)<<4));
        short8 bk = *(const short8*)((const char*)Ks + byte);
        sacc[n] = __builtin_amdgcn_mfma_f32_16x16x32_bf16(aq[kk], bk, sacc[n], 0,0,0);
      }
    }
    // decay + scale -> Ps (fp32, swizzled)
    const int kj0 = kb*64;
    #pragma unroll
    for (int n=0;n<4;++n){
      int kj = kj0 + n*16 + ln;
      #pragma unroll
      for (int r=0;r<4;++r){
        int qi = q0 + w*16 + g*4 + r;
        int d = qi - kj;
        float p = 0.f;
        if (d >= 0) p = sacc[n][r] * scale * exp2f(lg2g*(float)d);
        int prow = w*16 + g*4 + r;
        int byte = prow*256 + ((((n*16+ln)*4)) ^ ((prow&7)<<4));
        *(float*)((char*)Ps + byte) = p;
      }
    }
    // PV (wave-local rows of Ps; same-wave write->read ordered by compiler)
    #pragma unroll
    for (int kk2=0;kk2<2;++kk2){
      int prow = w*16 + ln;
      int base = prow*256;
      int c0 = kk2*128 + g*32;
      int sw = (prow&7)<<4;
      f32x4 p0 = *(const f32x4*)((const char*)Ps + base + ((c0   )^sw));
      f32x4 p1 = *(const f32x4*)((const char*)Ps + base + ((c0+16)^sw));
      short8 ap;
      #pragma unroll
      for (int jj=0;jj<4;++jj){ ap[jj] = (short)f2bf(p0[jj]); ap[4+jj] = (short)f2bf(p1[jj]); }
      #pragma unroll
      for (int n2=0;n2<16;++n2){
        int vrow = n2*16 + ln;
        int byte = vrow*128 + ((kk2*64 + g*16) ^ ((vrow&7)<<4));
        short8 bv = *(const short8*)((const char*)Vt + byte);
        accO[n2] = __builtin_amdgcn_mfma_f32_16x16x32_bf16(ap, bv, accO[n2], 0,0,0);
      }
    }
    __syncthreads();
  }

  // epilogue: pre-scale by analytic row norm, atomic-accumulate into Of
  float inv4[4];
  #pragma unroll
  for (int r=0;r<4;++r){
    int qi = q0 + w*16 + g*4 + r;
    float rs = (1.f - exp2f(lg2g*(float)(qi+1))) / omg;
    inv4[r] = rsqrtf(fmaxf(rs, 1e-6f));
  }
  #pragma unroll
  for (int n2=0;n2<16;++n2){
    #pragma unroll
    for (int r=0;r<4;++r){
      float v = accO[n2][r]*inv4[r];
      atomicAdd(&Of[(size_t)(b*2048 + q0 + w*16 + g*4 + r)*1536 + h*256 + n2*16 + ln], v);
    }
  }
}

// ---------------- per-(b,h) stats over normalized Of ----------------
__global__ __launch_bounds__(256)
void k_stats(const float* __restrict__ Of, float* __restrict__ stats){
  const int bh = blockIdx.y, b = bh/6, h = bh%6;
  const int tid = threadIdx.x, w = tid>>6, l = tid&63;
  int tv = blockIdx.x*256 + tid;     // 65536 per bh
  int t = tv>>5, v0 = (tv&31)*8;
  const float* p = Of + (size_t)(b*2048 + t)*1536 + h*256 + v0;
  float4 a = *(const float4*)p;
  float4 c = *(const float4*)(p+4);
  float s = a.x+a.y+a.z+a.w + c.x+c.y+c.z+c.w;
  float q = a.x*a.x+a.y*a.y+a.z*a.z+a.w*a.w + c.x*c.x+c.y*c.y+c.z*c.z+c.w*c.w;
  #pragma unroll
  for (int o=32;o;o>>=1){ s += __shfl_xor(s,o,64); q += __shfl_xor(q,o,64); }
  __shared__ float red[8];
  if (l==0){ red[w*2] = s; red[w*2+1] = q; }
  __syncthreads();
  if (tid==0){
    float S = red[0]+red[2]+red[4]+red[6];
    float Q2 = red[1]+red[3]+red[5]+red[7];
    atomicAdd(&stats[bh*2], S);
    atomicAdd(&stats[bh*2+1], Q2);
  }
}

// ---------------- groupnorm + gate ----------------
__global__ void k_gatenorm(const float* __restrict__ Of, const u16* __restrict__ Gb,
                           const float* __restrict__ gnw, const float* __restrict__ gnb,
                           const float* __restrict__ stats, u16* __restrict__ Yb){
  size_t base = ((size_t)blockIdx.x*256 + threadIdx.x)*8;
  int m = (int)(base/1536);
  int c = (int)(base%1536);
  int bh = (m>>11)*6 + (c>>8);
  const float Ninv = 1.f/524288.f;
  float mean = stats[bh*2]*Ninv;
  float var = stats[bh*2+1]*Ninv - mean*mean;
  float rstd = rsqrtf(var + 1e-5f);
  #pragma unroll
  for (int jj=0;jj<8;++jj){
    float o = Of[base+jj];
    float nv = (o-mean)*rstd*gnw[c+jj] + gnb[c+jj];
    Yb[base+jj] = f2bf(nv * bf2f(Gb[base+jj]));
  }
}

// ---------------- launch ----------------
extern "C" void kernel_launch(void* const* d_in, const int* in_sizes, int n_in,
                              void* d_out, int out_size, void* d_ws, size_t ws_size,
                              hipStream_t stream)
{
  const float* x   = (const float*)d_in[0];
  const float* Wq  = (const float*)d_in[1];
  const float* Wk  = (const float*)d_in[2];
  const float* Wv  = (const float*)d_in[3];
  const float* Wg  = (const float*)d_in[4];
  const float* Wo  = (const float*)d_in[5];
  const float* gnw = (const float*)d_in[6];
  const float* gnb = (const float*)d_in[7];
  float* out = (float*)d_out;

  char* ws = (char*)d_ws;
  size_t off = 0;
  auto alloc = [&](size_t bytes){ char* p = ws + off; off += (bytes + 255) & ~(size_t)255; return p; };
  u16*  xb   = (u16*) alloc(4096ull*768*2);
  u16*  WT   = (u16*) alloc(4608ull*768*2);
  u16*  WoT  = (u16*) alloc(768ull*1536*2);
  u16*  Qr   = (u16*) alloc(4096ull*768*2);
  u16*  Kr   = (u16*) alloc(4096ull*768*2);
  u16*  Vraw = (u16*) alloc(4096ull*1536*2);
  u16*  VbT  = (u16*) alloc(4096ull*1536*2);
  u16*  Gb   = (u16*) alloc(4096ull*1536*2);
  float* Of  = (float*)alloc(4096ull*1536*4);
  u16*  Yb   = (u16*) alloc(4096ull*1536*2);
  float* stats = (float*)alloc(256);

  hipMemsetAsync(Of, 0, 4096ull*1536*4, stream);
  hipMemsetAsync(stats, 0, 256, stream);
  k_cvt_x<<<3072, 256, 0, stream>>>(x, xb);
  k_wtrans<<<dim3(24,24), dim3(32,8), 0, stream>>>(Wq, WT,              768, 768);
  k_wtrans<<<dim3(24,24), dim3(32,8), 0, stream>>>(Wk, WT + 768ull*768,  768, 768);
  k_wtrans<<<dim3(48,24), dim3(32,8), 0, stream>>>(Wv, WT + 1536ull*768, 1536, 768);
  k_wtrans<<<dim3(48,24), dim3(32,8), 0, stream>>>(Wg, WT + 3072ull*768, 1536, 768);
  k_wtrans<<<dim3(24,48), dim3(32,8), 0, stream>>>(Wo, WoT,              768, 1536);
  k_gemm<0,128><<<dim3(32,36), 256, 0, stream>>>(xb, WT, 768, 4608, Qr, Kr, Vraw, Gb, (float*)nullptr);
  k_xpos<<<6144, 256, 0, stream>>>(Qr,  1.f);
  k_xpos<<<6144, 256, 0, stream>>>(Kr, -1.f);
  k_vtrans<<<dim3(64,8,12), dim3(32,8), 0, stream>>>(Vraw, VbT);
  k_ret<<<dim3(80,12), 256, 0, stream>>>(Qr, Kr, VbT, Of);
  k_stats<<<dim3(256,12), 256, 0, stream>>>(Of, stats);
  k_gatenorm<<<3072, 256, 0, stream>>>(Of, Gb, gnw, gnb, stats, Yb);
  k_gemm<1,64><<<dim3(64,6), 256, 0, stream>>>(Yb, WoT, 1536, 768,
                                            (u16*)nullptr,(u16*)nullptr,(u16*)nullptr,(u16*)nullptr, out);
}

// Round 3
// 205.731 us; speedup vs baseline: 1.2324x; 1.2324x over previous
//
#include <hip/hip_runtime.h>

typedef unsigned short u16;
typedef unsigned int u32;
typedef __attribute__((ext_vector_type(8))) short short8;
typedef __attribute__((ext_vector_type(4))) float f32x4;

#define DEV static __device__ __forceinline__

DEV float bf2f(u16 u){ u32 i = ((u32)u)<<16; float f; __builtin_memcpy(&f,&i,4); return f; }
DEV u16 f2bf(float f){ u32 i; __builtin_memcpy(&i,&f,4); u32 r = i + 0x7FFFu + ((i>>16)&1u); return (u16)(r>>16); }

DEV void gld16(const void* gp, void* lp){
  __builtin_amdgcn_global_load_lds((const __attribute__((address_space(1))) void*)gp,
                                   (__attribute__((address_space(3))) void*)lp, 16, 0, 0);
}

// ---------------- utility kernels ----------------

__global__ void k_cvt_x(const float* __restrict__ x, u16* __restrict__ xb){
  size_t base = ((size_t)blockIdx.x*256 + threadIdx.x)*4;
  float4 v = *(const float4*)(x + base);
  ushort4 o; o.x=f2bf(v.x); o.y=f2bf(v.y); o.z=f2bf(v.z); o.w=f2bf(v.w);
  *(ushort4*)(xb + base) = o;
}

// src: K x N fp32 row-major  ->  dst: N x K bf16 row-major
__global__ void k_wtrans(const float* __restrict__ src, u16* __restrict__ dst, int N, int K){
  __shared__ float tile[32][33];
  int n0 = blockIdx.x*32, k0 = blockIdx.y*32;
  int tx = threadIdx.x, ty = threadIdx.y;
  #pragma unroll
  for (int i=0;i<4;++i)
    tile[ty + i*8][tx] = src[(size_t)(k0 + ty + i*8)*N + n0 + tx];
  __syncthreads();
  #pragma unroll
  for (int i=0;i<4;++i)
    dst[(size_t)(n0 + ty + i*8)*K + k0 + tx] = f2bf(tile[tx][ty + i*8]);
}

// Vraw [4096][1536] bf16 -> VbTs [(bh)*256+v][2048] bf16, scaled by gamma_h^(63-(t&63))
__global__ void k_vtrans(const u16* __restrict__ Vraw, u16* __restrict__ VbTs){
  __shared__ u16 tile[32][33];
  int bh = blockIdx.z, b = bh/6, h = bh%6;
  int t0 = blockIdx.x*32, v0 = blockIdx.y*32;
  int tx = threadIdx.x, ty = threadIdx.y;
  float lg2g = log2f(1.f - exp2f(-(float)(5+h)));
  float dec = exp2f(lg2g * (float)(63 - ((t0 + tx) & 63)));   // out column t = t0+tx
  #pragma unroll
  for (int i=0;i<4;++i)
    tile[ty+i*8][tx] = Vraw[(size_t)(b*2048 + t0 + ty + i*8)*1536 + h*256 + v0 + tx];
  __syncthreads();
  #pragma unroll
  for (int i=0;i<4;++i)
    VbTs[(size_t)(bh*256 + v0 + ty + i*8)*2048 + t0 + tx] = f2bf(bf2f(tile[tx][ty+i*8]) * dec);
}

// Kr [4096][768] bf16 -> KbT [(bh)*128+d][2048] bf16 (unscaled)
__global__ void k_ktrans(const u16* __restrict__ Kr, u16* __restrict__ KbT){
  __shared__ u16 tile[32][33];
  int bh = blockIdx.z, b = bh/6, h = bh%6;
  int t0 = blockIdx.x*32, d0 = blockIdx.y*32;
  int tx = threadIdx.x, ty = threadIdx.y;
  #pragma unroll
  for (int i=0;i<4;++i)
    tile[ty+i*8][tx] = Kr[(size_t)(b*2048 + t0 + ty + i*8)*768 + h*128 + d0 + tx];
  __syncthreads();
  #pragma unroll
  for (int i=0;i<4;++i)
    KbT[(size_t)(bh*128 + d0 + ty + i*8)*2048 + t0 + tx] = tile[tx][ty+i*8];
}

// xPos table: tab[t*64+j] = (cos*decq, sin*decq, cos*deck, sin*deck)
__global__ void k_xpostab(float4* __restrict__ tab){
  int idx = blockIdx.x*256 + threadIdx.x;   // 2048*64
  int t = idx>>6, j = idx&63;
  float inv_freq = expf(-(float)j * (9.210340371976184f/64.f));
  float angle = (float)t * inv_freq;
  float zeta = (float)(j + 64) * (1.f/128.f);
  float decq = exp2f(log2f(zeta) * ((float)t*(1.f/512.f)));
  float deck = 1.f/decq;
  float sn, cs; sincosf(angle, &sn, &cs);
  float4 o; o.x = cs*decq; o.y = sn*decq; o.z = cs*deck; o.w = sn*deck;
  tab[idx] = o;
}

// apply xPos to Q (sign +) and K (sign -) in place, 4 j's per thread
__global__ void k_xpos2(u16* __restrict__ Qr, u16* __restrict__ Kr, const float4* __restrict__ tab){
  int idx = blockIdx.x*256 + threadIdx.x;   // m*96 + h*16 + jg
  int jg = idx & 15;
  int h  = (idx>>4) % 6;
  int m  = (idx>>4) / 6;
  int t  = m & 2047;
  size_t base = (size_t)m*768 + h*128 + jg*4;
  ushort4 q1 = *(const ushort4*)(Qr + base);
  ushort4 q2 = *(const ushort4*)(Qr + base + 64);
  ushort4 k1 = *(const ushort4*)(Kr + base);
  ushort4 k2 = *(const ushort4*)(Kr + base + 64);
  ushort4 oq1, oq2, ok1, ok2;
  const float4* tb = tab + t*64 + jg*4;
  #pragma unroll
  for (int jj=0;jj<4;++jj){
    float4 f = tb[jj];
    float a, b2;
    a = bf2f(((const u16*)&q1)[jj]); b2 = bf2f(((const u16*)&q2)[jj]);
    ((u16*)&oq1)[jj] = f2bf(a*f.x - b2*f.y);
    ((u16*)&oq2)[jj] = f2bf(a*f.y + b2*f.x);
    a = bf2f(((const u16*)&k1)[jj]); b2 = bf2f(((const u16*)&k2)[jj]);
    ((u16*)&ok1)[jj] = f2bf(a*f.z - b2*f.w);
    ((u16*)&ok2)[jj] = f2bf(a*f.w + b2*f.z);
  }
  *(ushort4*)(Qr + base)      = oq1;
  *(ushort4*)(Qr + base + 64) = oq2;
  *(ushort4*)(Kr + base)      = ok1;
  *(ushort4*)(Kr + base + 64) = ok2;
}

// ---------------- GEMM: C[M,N] = A[M,K] * BT[N,K]^T  (bf16 in, fp32 acc) ----------------
template<int MODE, int BM>
__global__ __launch_bounds__(256)
void k_gemm(const u16* __restrict__ A, const u16* __restrict__ BT,
            int K, int N,
            u16* __restrict__ Qr, u16* __restrict__ Kr,
            u16* __restrict__ Vraw, u16* __restrict__ Gb,
            float* __restrict__ Out)
{
  constexpr int MR = BM/32;
  __shared__ u16 As[BM*64];
  __shared__ u16 Bs[128*64];
  const int tid = threadIdx.x;
  const int w = tid>>6, l = tid&63, g = l>>4, ln = l&15;
  const int wr = w>>1, wc = w&1;
  const int m0 = blockIdx.x*BM, n0 = blockIdx.y*128;
  const f32x4 fz = {0.f,0.f,0.f,0.f};
  f32x4 acc[MR][4];
  #pragma unroll
  for (int m=0;m<MR;++m)
    #pragma unroll
    for (int n=0;n<4;++n) acc[m][n] = fz;

  const int nk = K>>6;
  for (int kt=0; kt<nk; ++kt){
    const int k0 = kt<<6;
    #pragma unroll
    for (int i=0;i<BM/32;++i){
      int off = i*4096 + tid*16;
      int row = off>>7;
      int colb = (((off>>4)&7)<<4) ^ ((row&7)<<4);
      gld16(A  + (size_t)(m0+row)*K + k0 + (colb>>1), (char*)As + i*4096 + w*1024);
    }
    #pragma unroll
    for (int i=0;i<4;++i){
      int off = i*4096 + tid*16;
      int row = off>>7;
      int colb = (((off>>4)&7)<<4) ^ ((row&7)<<4);
      gld16(BT + (size_t)(n0+row)*K + k0 + (colb>>1), (char*)Bs + i*4096 + w*1024);
    }
    __syncthreads();
    #pragma unroll
    for (int kk=0;kk<2;++kk){
      short8 a[MR], b[4];
      #pragma unroll
      for (int m=0;m<MR;++m){
        int row = wr*(BM/2) + m*16 + ln;
        int byte = row*128 + ((kk*64 + g*16) ^ ((row&7)<<4));
        a[m] = *(const short8*)((const char*)As + byte);
      }
      #pragma unroll
      for (int n=0;n<4;++n){
        int row = wc*64 + n*16 + ln;
        int byte = row*128 + ((kk*64 + g*16) ^ ((row&7)<<4));
        b[n] = *(const short8*)((const char*)Bs + byte);
      }
      #pragma unroll
      for (int m=0;m<MR;++m)
        #pragma unroll
        for (int n=0;n<4;++n)
          acc[m][n] = __builtin_amdgcn_mfma_f32_16x16x32_bf16(a[m], b[n], acc[m][n], 0,0,0);
    }
    __syncthreads();
  }
  const int region = n0/768;
  #pragma unroll
  for (int m=0;m<MR;++m){
    int grow0 = m0 + wr*(BM/2) + m*16 + g*4;
    #pragma unroll
    for (int n=0;n<4;++n){
      int c = n0 + wc*64 + n*16 + ln;
      #pragma unroll
      for (int r=0;r<4;++r){
        float v = acc[m][n][r];
        size_t grow = (size_t)(grow0 + r);
        if (MODE == 1){
          Out[grow*(size_t)N + c] = v;
        } else {
          if (region==0)      Qr[grow*768 + c] = f2bf(v);
          else if (region==1) Kr[grow*768 + (c-768)] = f2bf(v);
          else if (region<4)  Vraw[grow*1536 + (c-1536)] = f2bf(v);
          else { float sg = v/(1.f+__expf(-v)); Gb[grow*1536 + (c-3072)] = f2bf(sg); }
        }
      }
    }
  }
}

// ---------------- pass A: per-chunk Z_c^T[v][d] = sum_a Vs^T[v][a] * K^T[d][a] ----------------
// grid (31, 12): c, bh. 256 thr = 4 waves; wave owns 64 v-rows x 128 d.
__global__ __launch_bounds__(256)
void k_passA(const u16* __restrict__ VbTs, const u16* __restrict__ KbT, u16* __restrict__ Zb)
{
  __shared__ u16 Kt[128*64];   // K^T tile [d][a], 16 KB, swizzled
  __shared__ u16 Vt[256*64];   // Vs^T tile [v][a], 32 KB, swizzled
  const int tid = threadIdx.x, w = tid>>6, l = tid&63, g = l>>4, ln = l&15;
  const int c = blockIdx.x, bh = blockIdx.y;
  const f32x4 fz = {0.f,0.f,0.f,0.f};

  #pragma unroll
  for (int i=0;i<4;++i){       // K^T: 128 rows x 64 a (128B rows)
    int off = i*4096 + tid*16;
    int row = off>>7;
    int colb = (((off>>4)&7)<<4) ^ ((row&7)<<4);
    gld16(KbT + (size_t)(bh*128 + row)*2048 + c*64 + (colb>>1), (char*)Kt + i*4096 + w*1024);
  }
  #pragma unroll
  for (int i=0;i<8;++i){       // Vs^T: 256 rows x 64 a
    int off = i*4096 + tid*16;
    int row = off>>7;
    int colb = (((off>>4)&7)<<4) ^ ((row&7)<<4);
    gld16(VbTs + (size_t)(bh*256 + row)*2048 + c*64 + (colb>>1), (char*)Vt + i*4096 + w*1024);
  }
  __syncthreads();

  f32x4 acc[4][8];
  #pragma unroll
  for (int m=0;m<4;++m)
    #pragma unroll
    for (int n=0;n<8;++n) acc[m][n] = fz;

  #pragma unroll
  for (int kk=0;kk<2;++kk){
    short8 va[4], kb[8];
    #pragma unroll
    for (int m=0;m<4;++m){
      int vrow = w*64 + m*16 + ln;
      int byte = vrow*128 + ((kk*64 + g*16) ^ ((vrow&7)<<4));
      va[m] = *(const short8*)((const char*)Vt + byte);
    }
    #pragma unroll
    for (int n=0;n<8;++n){
      int krow = n*16 + ln;
      int byte = krow*128 + ((kk*64 + g*16) ^ ((krow&7)<<4));
      kb[n] = *(const short8*)((const char*)Kt + byte);
    }
    #pragma unroll
    for (int m=0;m<4;++m)
      #pragma unroll
      for (int n=0;n<8;++n)
        acc[m][n] = __builtin_amdgcn_mfma_f32_16x16x32_bf16(va[m], kb[n], acc[m][n], 0,0,0);
  }

  u16* z = Zb + (size_t)(c*12 + bh)*32768;
  #pragma unroll
  for (int m=0;m<4;++m)
    #pragma unroll
    for (int n=0;n<8;++n)
      #pragma unroll
      for (int r=0;r<4;++r){
        int v = w*64 + m*16 + g*4 + r;
        int d = n*16 + ln;
        z[v*128 + d] = f2bf(acc[m][n][r]);
      }
}

// ---------------- scan: States[c] = gamma^64 * States[c-1] + Z[c-1], States[0]=0 ----------------
// grid (16, 12), 128 thr; each thread owns 16 consecutive elements.
__global__ __launch_bounds__(128)
void k_scan(const u16* __restrict__ Zb, u16* __restrict__ States)
{
  const int bh = blockIdx.y, h = bh%6;
  const int e0 = blockIdx.x*2048 + threadIdx.x*16;
  const float lg2g = log2f(1.f - exp2f(-(float)(5+h)));
  const float gl = exp2f(lg2g * 64.f);
  float S[16];
  #pragma unroll
  for (int j=0;j<16;++j) S[j] = 0.f;
  // States[0] = 0
  {
    short8 zz = {0,0,0,0,0,0,0,0};
    u16* o = States + (size_t)bh*32768 + e0;
    *(short8*)o = zz; *(short8*)(o+8) = zz;
  }
  for (int c=1;c<32;++c){
    const u16* z = Zb + (size_t)((c-1)*12 + bh)*32768 + e0;
    short8 z0 = *(const short8*)z;
    short8 z1 = *(const short8*)(z+8);
    #pragma unroll
    for (int j=0;j<8;++j){ S[j]   = gl*S[j]   + bf2f((u16)z0[j]); }
    #pragma unroll
    for (int j=0;j<8;++j){ S[8+j] = gl*S[8+j] + bf2f((u16)z1[j]); }
    u16* o = States + (size_t)(c*12 + bh)*32768 + e0;
    short8 s0, s1;
    #pragma unroll
    for (int j=0;j<8;++j){ s0[j] = (short)f2bf(S[j]); s1[j] = (short)f2bf(S[8+j]); }
    *(short8*)o = s0; *(short8*)(o+8) = s1;
  }
}

// ---------------- pass C: O_c = scale*gamma^(a+1)*(Q@State^T + gamma^-64 * intra) * invnorm ----------------
// grid (32, 12): c, bh. 256 thr = 4 waves, 16 q-rows each. Direct stores + stats atomics.
__global__ __launch_bounds__(256)
void k_passC(const u16* __restrict__ Qb, const u16* __restrict__ Kb,
             const u16* __restrict__ VbTs, const u16* __restrict__ States,
             float* __restrict__ Of, float* __restrict__ stats)
{
  __shared__ u16 Ks[64*128];    // K_c tile [a][d], 16 KB
  __shared__ u16 Vt[256*64];    // Vs^T tile [v][a], 32 KB
  __shared__ float Ps[64*64];   // 16 KB
  const int tid = threadIdx.x, w = tid>>6, l = tid&63, g = l>>4, ln = l&15;
  const int c = blockIdx.x, bh = blockIdx.y, b = bh/6, h = bh%6;
  const float omg = exp2f(-(float)(5+h));
  const float gamma = 1.f - omg;
  const float lg2g = log2f(gamma);
  const float scale = 0.08838834764831845f; // 128^-0.5
  const int q0 = c*64;
  const f32x4 fz = {0.f,0.f,0.f,0.f};

  short8 aq[4];
  {
    const size_t qrow = (size_t)(b*2048 + q0 + w*16 + ln)*768 + h*128;
    #pragma unroll
    for (int kk=0;kk<4;++kk) aq[kk] = *(const short8*)(Qb + qrow + kk*32 + g*8);
  }

  #pragma unroll
  for (int i=0;i<4;++i){       // K tile: 64 rows x 128 d (256B rows)
    int off = i*4096 + tid*16;
    int row = off>>8;
    int colb = (((off>>4)&15)<<4) ^ ((row&7)<<4);
    gld16(Kb + (size_t)(b*2048 + q0 + row)*768 + h*128 + (colb>>1),
          (char*)Ks + i*4096 + w*1024);
  }
  #pragma unroll
  for (int i=0;i<8;++i){       // Vs^T tile: 256 rows x 64 keys
    int off = i*4096 + tid*16;
    int row = off>>7;
    int colb = (((off>>4)&7)<<4) ^ ((row&7)<<4);
    gld16(VbTs + (size_t)(bh*256 + row)*2048 + q0 + (colb>>1),
          (char*)Vt + i*4096 + w*1024);
  }
  __syncthreads();

  // S = Q K^T
  f32x4 sacc[4]; sacc[0]=fz; sacc[1]=fz; sacc[2]=fz; sacc[3]=fz;
  #pragma unroll
  for (int kk=0;kk<4;++kk){
    #pragma unroll
    for (int n=0;n<4;++n){
      int row = n*16 + ln;
      int byte = row*256 + ((kk*64 + g*16) ^ ((row&7)<<4));
      short8 bk = *(const short8*)((const char*)Ks + byte);
      sacc[n] = __builtin_amdgcn_mfma_f32_16x16x32_bf16(aq[kk], bk, sacc[n], 0,0,0);
    }
  }
  // causal mask only (decay folded into Vs + row factors) -> Ps
  #pragma unroll
  for (int n=0;n<4;++n){
    int kj = n*16 + ln;
    #pragma unroll
    for (int r=0;r<4;++r){
      int a = w*16 + g*4 + r;
      float p = (a >= kj) ? sacc[n][r] : 0.f;
      int prow = w*16 + g*4 + r;
      int byte = prow*256 + ((((n*16+ln)*4)) ^ ((prow&7)<<4));
      *(float*)((char*)Ps + byte) = p;
    }
  }
  // intra = P @ Vs
  f32x4 acc[16];
  #pragma unroll
  for (int i=0;i<16;++i) acc[i] = fz;
  #pragma unroll
  for (int kk2=0;kk2<2;++kk2){
    int prow = w*16 + ln;
    int base = prow*256;
    int c0 = kk2*128 + g*32;
    int sw = (prow&7)<<4;
    f32x4 p0 = *(const f32x4*)((const char*)Ps + base + ((c0   )^sw));
    f32x4 p1 = *(const f32x4*)((const char*)Ps + base + ((c0+16)^sw));
    short8 ap;
    #pragma unroll
    for (int jj=0;jj<4;++jj){ ap[jj] = (short)f2bf(p0[jj]); ap[4+jj] = (short)f2bf(p1[jj]); }
    #pragma unroll
    for (int n2=0;n2<16;++n2){
      int vrow = n2*16 + ln;
      int byte = vrow*128 + ((kk2*64 + g*16) ^ ((vrow&7)<<4));
      short8 bv = *(const short8*)((const char*)Vt + byte);
      acc[n2] = __builtin_amdgcn_mfma_f32_16x16x32_bf16(ap, bv, acc[n2], 0,0,0);
    }
  }
  // scale intra by gamma^-64, then accumulate cross = Q @ State^T on top
  const float gi64 = exp2f(-64.f*lg2g);
  #pragma unroll
  for (int i=0;i<16;++i){ acc[i][0]*=gi64; acc[i][1]*=gi64; acc[i][2]*=gi64; acc[i][3]*=gi64; }
  const u16* st = States + (size_t)(c*12 + bh)*32768;
  #pragma unroll
  for (int kk=0;kk<4;++kk){
    #pragma unroll
    for (int n2=0;n2<16;++n2){
      short8 sb = *(const short8*)(st + (n2*16 + ln)*128 + kk*32 + g*8);
      acc[n2] = __builtin_amdgcn_mfma_f32_16x16x32_bf16(aq[kk], sb, acc[n2], 0,0,0);
    }
  }
  // epilogue: row factor = scale * gamma^(a+1) * rsqrt(rowsum), direct store + stats
  float rf[4];
  #pragma unroll
  for (int r=0;r<4;++r){
    int a = w*16 + g*4 + r;
    int qi = q0 + a;
    float rs = (1.f - exp2f(lg2g*(float)(qi+1))) / omg;
    rf[r] = scale * exp2f(lg2g*(float)(a+1)) * rsqrtf(fmaxf(rs, 1e-6f));
  }
  float lsum=0.f, lsq=0.f;
  #pragma unroll
  for (int n2=0;n2<16;++n2){
    #pragma unroll
    for (int r=0;r<4;++r){
      float v = acc[n2][r]*rf[r];
      Of[(size_t)(b*2048 + q0 + w*16 + g*4 + r)*1536 + h*256 + n2*16 + ln] = v;
      lsum += v; lsq += v*v;
    }
  }
  #pragma unroll
  for (int o=32;o;o>>=1){ lsum += __shfl_xor(lsum,o,64); lsq += __shfl_xor(lsq,o,64); }
  if (l==0){ atomicAdd(&stats[bh*2], lsum); atomicAdd(&stats[bh*2+1], lsq); }
}

// ---------------- groupnorm + gate ----------------
__global__ void k_gatenorm(const float* __restrict__ Of, const u16* __restrict__ Gb,
                           const float* __restrict__ gnw, const float* __restrict__ gnb,
                           const float* __restrict__ stats, u16* __restrict__ Yb){
  size_t base = ((size_t)blockIdx.x*256 + threadIdx.x)*8;
  int m = (int)(base/1536);
  int c = (int)(base%1536);
  int bh = (m>>11)*6 + (c>>8);
  const float Ninv = 1.f/524288.f;
  float mean = stats[bh*2]*Ninv;
  float var = stats[bh*2+1]*Ninv - mean*mean;
  float rstd = rsqrtf(var + 1e-5f);
  #pragma unroll
  for (int jj=0;jj<8;++jj){
    float o = Of[base+jj];
    float nv = (o-mean)*rstd*gnw[c+jj] + gnb[c+jj];
    Yb[base+jj] = f2bf(nv * bf2f(Gb[base+jj]));
  }
}

// ---------------- launch ----------------
extern "C" void kernel_launch(void* const* d_in, const int* in_sizes, int n_in,
                              void* d_out, int out_size, void* d_ws, size_t ws_size,
                              hipStream_t stream)
{
  const float* x   = (const float*)d_in[0];
  const float* Wq  = (const float*)d_in[1];
  const float* Wk  = (const float*)d_in[2];
  const float* Wv  = (const float*)d_in[3];
  const float* Wg  = (const float*)d_in[4];
  const float* Wo  = (const float*)d_in[5];
  const float* gnw = (const float*)d_in[6];
  const float* gnb = (const float*)d_in[7];
  float* out = (float*)d_out;

  // Aliased workspace layout (live ranges verified):
  // [0 .. 25.95M): xb | WT | Vraw  (all dead before k_scan) — later States, tab, Yb, KbT
  char* ws = (char*)d_ws;
  u16*   xb     = (u16*)  (ws + 0);          // [cvt -> gemm0]
  u16*   WT     = (u16*)  (ws + 6291456);    // [wtrans -> gemm0]
  u16*   Vraw   = (u16*)  (ws + 13369344);   // [gemm0 -> vtrans]
  float4* tab   = (float4*)(ws + 0);         // [xpostab -> xpos2] (over dead xb)
  u16*   KbT    = (u16*)  (ws + 6291456);    // [ktrans -> passA] (over dead WT)
  u16*   States = (u16*)  (ws + 0);          // [scan -> passC] (over dead xb/WT/Vraw)
  u16*   Yb     = (u16*)  (ws + 0);          // [gatenorm -> gemm1] (over dead States)
  u16*   Kr     = (u16*)  (ws + 25952256);   // [gemm0 -> passC]
  u16*   Qr     = (u16*)  (ws + 32243712);   // [gemm0 -> passC]
  u16*   Gb     = (u16*)  (ws + 38535168);   // [gemm0 -> gatenorm]
  u16*   WoT    = (u16*)  (ws + 51118080);   // [wtrans -> gemm1]
  u16*   VbTs   = (u16*)  (ws + 53477376);   // [vtrans -> passC]
  u16*   Zb     = (u16*)  (ws + 66060288);   // [passA -> scan]
  float* Of     = (float*)(ws + 66060288);   // [passC -> gatenorm] (over dead Zb)
  float* stats  = (float*)(ws + 91226112);

  hipMemsetAsync(stats, 0, 256, stream);
  k_cvt_x<<<3072, 256, 0, stream>>>(x, xb);
  k_wtrans<<<dim3(24,24), dim3(32,8), 0, stream>>>(Wq, WT,              768, 768);
  k_wtrans<<<dim3(24,24), dim3(32,8), 0, stream>>>(Wk, WT + 768ull*768,  768, 768);
  k_wtrans<<<dim3(48,24), dim3(32,8), 0, stream>>>(Wv, WT + 1536ull*768, 1536, 768);
  k_wtrans<<<dim3(48,24), dim3(32,8), 0, stream>>>(Wg, WT + 3072ull*768, 1536, 768);
  k_wtrans<<<dim3(24,48), dim3(32,8), 0, stream>>>(Wo, WoT,              768, 1536);
  k_gemm<0,128><<<dim3(32,36), 256, 0, stream>>>(xb, WT, 768, 4608, Qr, Kr, Vraw, Gb, (float*)nullptr);
  k_xpostab<<<512, 256, 0, stream>>>(tab);
  k_xpos2<<<1536, 256, 0, stream>>>(Qr, Kr, tab);
  k_vtrans<<<dim3(64,8,12), dim3(32,8), 0, stream>>>(Vraw, VbTs);
  k_ktrans<<<dim3(64,4,12), dim3(32,8), 0, stream>>>(Kr, KbT);
  k_passA<<<dim3(31,12), 256, 0, stream>>>(VbTs, KbT, Zb);
  k_scan<<<dim3(16,12), 128, 0, stream>>>(Zb, States);
  k_passC<<<dim3(32,12), 256, 0, stream>>>(Qr, Kr, VbTs, States, Of, stats);
  k_gatenorm<<<3072, 256, 0, stream>>>(Of, Gb, gnw, gnb, stats, Yb);
  k_gemm<1,64><<<dim3(64,6), 256, 0, stream>>>(Yb, WoT, 1536, 768,
                                            (u16*)nullptr,(u16*)nullptr,(u16*)nullptr,(u16*)nullptr, out);
}

// Round 4
// 160.808 us; speedup vs baseline: 1.5767x; 1.2794x over previous
//
#include <hip/hip_runtime.h>

typedef unsigned short u16;
typedef unsigned int u32;
typedef __attribute__((ext_vector_type(8))) short short8;
typedef __attribute__((ext_vector_type(4))) float f32x4;

#define DEV static __device__ __forceinline__

DEV float bf2f(u16 u){ u32 i = ((u32)u)<<16; float f; __builtin_memcpy(&f,&i,4); return f; }
DEV u16 f2bf(float f){ u32 i; __builtin_memcpy(&i,&f,4); u32 r = i + 0x7FFFu + ((i>>16)&1u); return (u16)(r>>16); }

DEV void gld16(const void* gp, void* lp){
  __builtin_amdgcn_global_load_lds((const __attribute__((address_space(1))) void*)gp,
                                   (__attribute__((address_space(3))) void*)lp, 16, 0, 0);
}

// ---------------- utility kernels ----------------

__global__ void k_cvt_x(const float* __restrict__ x, u16* __restrict__ xb){
  size_t base = ((size_t)blockIdx.x*256 + threadIdx.x)*4;
  float4 v = *(const float4*)(x + base);
  ushort4 o; o.x=f2bf(v.x); o.y=f2bf(v.y); o.z=f2bf(v.z); o.w=f2bf(v.w);
  *(ushort4*)(xb + base) = o;
}

// All five weight transposes in one launch. src: K x N fp32 -> dst: N x K bf16.
__global__ void k_wtrans_all(const float* __restrict__ Wq, const float* __restrict__ Wk,
                             const float* __restrict__ Wv, const float* __restrict__ Wg,
                             const float* __restrict__ Wo,
                             u16* __restrict__ WT, u16* __restrict__ WoT){
  __shared__ float tile[32][33];
  int i = blockIdx.x;
  const float* src; u16* dst; int N, K, bx, by;
  if (i < 576)       { src=Wq; dst=WT;                N=768;  K=768;  int j=i;      bx=j%24; by=j/24; }
  else if (i < 1152) { src=Wk; dst=WT+768ull*768;     N=768;  K=768;  int j=i-576;  bx=j%24; by=j/24; }
  else if (i < 2304) { src=Wv; dst=WT+1536ull*768;    N=1536; K=768;  int j=i-1152; bx=j%48; by=j/48; }
  else if (i < 3456) { src=Wg; dst=WT+3072ull*768;    N=1536; K=768;  int j=i-2304; bx=j%48; by=j/48; }
  else               { src=Wo; dst=WoT;               N=768;  K=1536; int j=i-3456; bx=j%24; by=j/24; }
  int n0 = bx*32, k0 = by*32;
  int tx = threadIdx.x, ty = threadIdx.y;
  #pragma unroll
  for (int q=0;q<4;++q)
    tile[ty + q*8][tx] = src[(size_t)(k0 + ty + q*8)*N + n0 + tx];
  __syncthreads();
  #pragma unroll
  for (int q=0;q<4;++q)
    dst[(size_t)(n0 + ty + q*8)*K + k0 + tx] = f2bf(tile[tx][ty + q*8]);
}

// Vraw [4096][1536] bf16 -> VbTs [(bh)*256+v][2048] bf16, scaled by gamma_h^(63-(t&63))
__global__ void k_vtrans(const u16* __restrict__ Vraw, u16* __restrict__ VbTs){
  __shared__ u16 tile[32][33];
  int bh = blockIdx.z, b = bh/6, h = bh%6;
  int t0 = blockIdx.x*32, v0 = blockIdx.y*32;
  int tx = threadIdx.x, ty = threadIdx.y;
  float lg2g = log2f(1.f - exp2f(-(float)(5+h)));
  float dec = exp2f(lg2g * (float)(63 - ((t0 + tx) & 63)));   // out column t = t0+tx
  #pragma unroll
  for (int i=0;i<4;++i)
    tile[ty+i*8][tx] = Vraw[(size_t)(b*2048 + t0 + ty + i*8)*1536 + h*256 + v0 + tx];
  __syncthreads();
  #pragma unroll
  for (int i=0;i<4;++i)
    VbTs[(size_t)(bh*256 + v0 + ty + i*8)*2048 + t0 + tx] = f2bf(bf2f(tile[tx][ty+i*8]) * dec);
}

// Kr [4096][768] bf16 -> KbT [(bh)*128+d][2048] bf16 (unscaled)
__global__ void k_ktrans(const u16* __restrict__ Kr, u16* __restrict__ KbT){
  __shared__ u16 tile[32][33];
  int bh = blockIdx.z, b = bh/6, h = bh%6;
  int t0 = blockIdx.x*32, d0 = blockIdx.y*32;
  int tx = threadIdx.x, ty = threadIdx.y;
  #pragma unroll
  for (int i=0;i<4;++i)
    tile[ty+i*8][tx] = Kr[(size_t)(b*2048 + t0 + ty + i*8)*768 + h*128 + d0 + tx];
  __syncthreads();
  #pragma unroll
  for (int i=0;i<4;++i)
    KbT[(size_t)(bh*128 + d0 + ty + i*8)*2048 + t0 + tx] = tile[tx][ty+i*8];
}

// xPos table: tab[t*64+j] = (cos*decq, sin*decq, cos*deck, sin*deck)
__global__ void k_xpostab(float4* __restrict__ tab){
  int idx = blockIdx.x*256 + threadIdx.x;   // 2048*64
  int t = idx>>6, j = idx&63;
  float inv_freq = expf(-(float)j * (9.210340371976184f/64.f));
  float angle = (float)t * inv_freq;
  float zeta = (float)(j + 64) * (1.f/128.f);
  float decq = exp2f(log2f(zeta) * ((float)t*(1.f/512.f)));
  float deck = 1.f/decq;
  float sn, cs; sincosf(angle, &sn, &cs);
  float4 o; o.x = cs*decq; o.y = sn*decq; o.z = cs*deck; o.w = sn*deck;
  tab[idx] = o;
}

// apply xPos to Q (sign +) and K (sign -) in place, 4 j's per thread
__global__ void k_xpos2(u16* __restrict__ Qr, u16* __restrict__ Kr, const float4* __restrict__ tab){
  int idx = blockIdx.x*256 + threadIdx.x;   // m*96 + h*16 + jg
  int jg = idx & 15;
  int h  = (idx>>4) % 6;
  int m  = (idx>>4) / 6;
  int t  = m & 2047;
  size_t base = (size_t)m*768 + h*128 + jg*4;
  ushort4 q1 = *(const ushort4*)(Qr + base);
  ushort4 q2 = *(const ushort4*)(Qr + base + 64);
  ushort4 k1 = *(const ushort4*)(Kr + base);
  ushort4 k2 = *(const ushort4*)(Kr + base + 64);
  ushort4 oq1, oq2, ok1, ok2;
  const float4* tb = tab + t*64 + jg*4;
  #pragma unroll
  for (int jj=0;jj<4;++jj){
    float4 f = tb[jj];
    float a, b2;
    a = bf2f(((const u16*)&q1)[jj]); b2 = bf2f(((const u16*)&q2)[jj]);
    ((u16*)&oq1)[jj] = f2bf(a*f.x - b2*f.y);
    ((u16*)&oq2)[jj] = f2bf(a*f.y + b2*f.x);
    a = bf2f(((const u16*)&k1)[jj]); b2 = bf2f(((const u16*)&k2)[jj]);
    ((u16*)&ok1)[jj] = f2bf(a*f.z - b2*f.w);
    ((u16*)&ok2)[jj] = f2bf(a*f.w + b2*f.z);
  }
  *(ushort4*)(Qr + base)      = oq1;
  *(ushort4*)(Qr + base + 64) = oq2;
  *(ushort4*)(Kr + base)      = ok1;
  *(ushort4*)(Kr + base + 64) = ok2;
}

// ---------------- GEMM: C[M,N] = A[M,K] * BT[N,K]^T  (bf16 in, fp32 acc) ----------------
template<int MODE, int BM>
__global__ __launch_bounds__(256)
void k_gemm(const u16* __restrict__ A, const u16* __restrict__ BT,
            int K, int N,
            u16* __restrict__ Qr, u16* __restrict__ Kr,
            u16* __restrict__ Vraw, u16* __restrict__ Gb,
            float* __restrict__ Out)
{
  constexpr int MR = BM/32;
  __shared__ u16 As[BM*64];
  __shared__ u16 Bs[128*64];
  const int tid = threadIdx.x;
  const int w = tid>>6, l = tid&63, g = l>>4, ln = l&15;
  const int wr = w>>1, wc = w&1;
  const int m0 = blockIdx.x*BM, n0 = blockIdx.y*128;
  const f32x4 fz = {0.f,0.f,0.f,0.f};
  f32x4 acc[MR][4];
  #pragma unroll
  for (int m=0;m<MR;++m)
    #pragma unroll
    for (int n=0;n<4;++n) acc[m][n] = fz;

  const int nk = K>>6;
  for (int kt=0; kt<nk; ++kt){
    const int k0 = kt<<6;
    #pragma unroll
    for (int i=0;i<BM/32;++i){
      int off = i*4096 + tid*16;
      int row = off>>7;
      int colb = (((off>>4)&7)<<4) ^ ((row&7)<<4);
      gld16(A  + (size_t)(m0+row)*K + k0 + (colb>>1), (char*)As + i*4096 + w*1024);
    }
    #pragma unroll
    for (int i=0;i<4;++i){
      int off = i*4096 + tid*16;
      int row = off>>7;
      int colb = (((off>>4)&7)<<4) ^ ((row&7)<<4);
      gld16(BT + (size_t)(n0+row)*K + k0 + (colb>>1), (char*)Bs + i*4096 + w*1024);
    }
    __syncthreads();
    #pragma unroll
    for (int kk=0;kk<2;++kk){
      short8 a[MR], b[4];
      #pragma unroll
      for (int m=0;m<MR;++m){
        int row = wr*(BM/2) + m*16 + ln;
        int byte = row*128 + ((kk*64 + g*16) ^ ((row&7)<<4));
        a[m] = *(const short8*)((const char*)As + byte);
      }
      #pragma unroll
      for (int n=0;n<4;++n){
        int row = wc*64 + n*16 + ln;
        int byte = row*128 + ((kk*64 + g*16) ^ ((row&7)<<4));
        b[n] = *(const short8*)((const char*)Bs + byte);
      }
      #pragma unroll
      for (int m=0;m<MR;++m)
        #pragma unroll
        for (int n=0;n<4;++n)
          acc[m][n] = __builtin_amdgcn_mfma_f32_16x16x32_bf16(a[m], b[n], acc[m][n], 0,0,0);
    }
    __syncthreads();
  }
  const int region = n0/768;
  #pragma unroll
  for (int m=0;m<MR;++m){
    int grow0 = m0 + wr*(BM/2) + m*16 + g*4;
    #pragma unroll
    for (int n=0;n<4;++n){
      int c = n0 + wc*64 + n*16 + ln;
      #pragma unroll
      for (int r=0;r<4;++r){
        float v = acc[m][n][r];
        size_t grow = (size_t)(grow0 + r);
        if (MODE == 1){
          Out[grow*(size_t)N + c] = v;
        } else {
          if (region==0)      Qr[grow*768 + c] = f2bf(v);
          else if (region==1) Kr[grow*768 + (c-768)] = f2bf(v);
          else if (region<4)  Vraw[grow*1536 + (c-1536)] = f2bf(v);
          else { float sg = v/(1.f+__expf(-v)); Gb[grow*1536 + (c-3072)] = f2bf(sg); }
        }
      }
    }
  }
}

// ---------------- pass A: per-chunk Z_c^T[v][d] = sum_a Vs^T[v][a] * K^T[d][a] ----------------
__global__ __launch_bounds__(256)
void k_passA(const u16* __restrict__ VbTs, const u16* __restrict__ KbT, u16* __restrict__ Zb)
{
  __shared__ u16 Kt[128*64];
  __shared__ u16 Vt[256*64];
  const int tid = threadIdx.x, w = tid>>6, l = tid&63, g = l>>4, ln = l&15;
  const int c = blockIdx.x, bh = blockIdx.y;
  const f32x4 fz = {0.f,0.f,0.f,0.f};

  #pragma unroll
  for (int i=0;i<4;++i){
    int off = i*4096 + tid*16;
    int row = off>>7;
    int colb = (((off>>4)&7)<<4) ^ ((row&7)<<4);
    gld16(KbT + (size_t)(bh*128 + row)*2048 + c*64 + (colb>>1), (char*)Kt + i*4096 + w*1024);
  }
  #pragma unroll
  for (int i=0;i<8;++i){
    int off = i*4096 + tid*16;
    int row = off>>7;
    int colb = (((off>>4)&7)<<4) ^ ((row&7)<<4);
    gld16(VbTs + (size_t)(bh*256 + row)*2048 + c*64 + (colb>>1), (char*)Vt + i*4096 + w*1024);
  }
  __syncthreads();

  f32x4 acc[4][8];
  #pragma unroll
  for (int m=0;m<4;++m)
    #pragma unroll
    for (int n=0;n<8;++n) acc[m][n] = fz;

  #pragma unroll
  for (int kk=0;kk<2;++kk){
    short8 va[4], kb[8];
    #pragma unroll
    for (int m=0;m<4;++m){
      int vrow = w*64 + m*16 + ln;
      int byte = vrow*128 + ((kk*64 + g*16) ^ ((vrow&7)<<4));
      va[m] = *(const short8*)((const char*)Vt + byte);
    }
    #pragma unroll
    for (int n=0;n<8;++n){
      int krow = n*16 + ln;
      int byte = krow*128 + ((kk*64 + g*16) ^ ((krow&7)<<4));
      kb[n] = *(const short8*)((const char*)Kt + byte);
    }
    #pragma unroll
    for (int m=0;m<4;++m)
      #pragma unroll
      for (int n=0;n<8;++n)
        acc[m][n] = __builtin_amdgcn_mfma_f32_16x16x32_bf16(va[m], kb[n], acc[m][n], 0,0,0);
  }

  u16* z = Zb + (size_t)(c*12 + bh)*32768;
  #pragma unroll
  for (int m=0;m<4;++m)
    #pragma unroll
    for (int n=0;n<8;++n)
      #pragma unroll
      for (int r=0;r<4;++r){
        int v = w*64 + m*16 + g*4 + r;
        int d = n*16 + ln;
        z[v*128 + d] = f2bf(acc[m][n][r]);
      }
}

// ---------------- scan: all 31 chunk-loads issued up-front, recurrence in registers ----------------
// grid 384 x 256: thread owns 4 consecutive elems of one bh (8192 threads/bh).
__global__ __launch_bounds__(256)
void k_scan(const u16* __restrict__ Zb, u16* __restrict__ States)
{
  int gid = blockIdx.x*256 + threadIdx.x;
  int bh = gid >> 13;            // /8192
  int e0 = (gid & 8191) * 4;
  const int h = bh % 6;
  const float lg2g = log2f(1.f - exp2f(-(float)(5+h)));
  const float gl = exp2f(lg2g * 64.f);
  ushort4 z[31];
  #pragma unroll
  for (int c=0;c<31;++c)
    z[c] = *(const ushort4*)(Zb + (size_t)(c*12 + bh)*32768 + e0);
  {
    ushort4 o; o.x=0;o.y=0;o.z=0;o.w=0;
    *(ushort4*)(States + (size_t)bh*32768 + e0) = o;
  }
  float S0=0.f,S1=0.f,S2=0.f,S3=0.f;
  #pragma unroll
  for (int c=1;c<32;++c){
    ushort4 zz = z[c-1];
    S0 = gl*S0 + bf2f(zz.x); S1 = gl*S1 + bf2f(zz.y);
    S2 = gl*S2 + bf2f(zz.z); S3 = gl*S3 + bf2f(zz.w);
    ushort4 o; o.x=f2bf(S0); o.y=f2bf(S1); o.z=f2bf(S2); o.w=f2bf(S3);
    *(ushort4*)(States + (size_t)(c*12 + bh)*32768 + e0) = o;
  }
}

// ---------------- pass C ----------------
// grid (32, 12). Per-block partial stats -> partials[(c*12+bh)*2 + {0,1}] (no atomics).
__global__ __launch_bounds__(256)
void k_passC(const u16* __restrict__ Qb, const u16* __restrict__ Kb,
             const u16* __restrict__ VbTs, const u16* __restrict__ States,
             float* __restrict__ Of, float* __restrict__ partials)
{
  __shared__ u16 Ks[64*128];
  __shared__ u16 Vt[256*64];
  __shared__ float Ps[64*64];
  __shared__ float red[8];
  const int tid = threadIdx.x, w = tid>>6, l = tid&63, g = l>>4, ln = l&15;
  const int c = blockIdx.x, bh = blockIdx.y, b = bh/6, h = bh%6;
  const float omg = exp2f(-(float)(5+h));
  const float gamma = 1.f - omg;
  const float lg2g = log2f(gamma);
  const float scale = 0.08838834764831845f; // 128^-0.5
  const int q0 = c*64;
  const f32x4 fz = {0.f,0.f,0.f,0.f};

  short8 aq[4];
  {
    const size_t qrow = (size_t)(b*2048 + q0 + w*16 + ln)*768 + h*128;
    #pragma unroll
    for (int kk=0;kk<4;++kk) aq[kk] = *(const short8*)(Qb + qrow + kk*32 + g*8);
  }

  #pragma unroll
  for (int i=0;i<4;++i){
    int off = i*4096 + tid*16;
    int row = off>>8;
    int colb = (((off>>4)&15)<<4) ^ ((row&7)<<4);
    gld16(Kb + (size_t)(b*2048 + q0 + row)*768 + h*128 + (colb>>1),
          (char*)Ks + i*4096 + w*1024);
  }
  #pragma unroll
  for (int i=0;i<8;++i){
    int off = i*4096 + tid*16;
    int row = off>>7;
    int colb = (((off>>4)&7)<<4) ^ ((row&7)<<4);
    gld16(VbTs + (size_t)(bh*256 + row)*2048 + q0 + (colb>>1),
          (char*)Vt + i*4096 + w*1024);
  }
  __syncthreads();

  // S = Q K^T
  f32x4 sacc[4]; sacc[0]=fz; sacc[1]=fz; sacc[2]=fz; sacc[3]=fz;
  #pragma unroll
  for (int kk=0;kk<4;++kk){
    #pragma unroll
    for (int n=0;n<4;++n){
      int row = n*16 + ln;
      int byte = row*256 + ((kk*64 + g*16) ^ ((row&7)<<4));
      short8 bk = *(const short8*)((const char*)Ks + byte);
      sacc[n] = __builtin_amdgcn_mfma_f32_16x16x32_bf16(aq[kk], bk, sacc[n], 0,0,0);
    }
  }
  // causal mask only -> Ps
  #pragma unroll
  for (int n=0;n<4;++n){
    int kj = n*16 + ln;
    #pragma unroll
    for (int r=0;r<4;++r){
      int a = w*16 + g*4 + r;
      float p = (a >= kj) ? sacc[n][r] : 0.f;
      int prow = w*16 + g*4 + r;
      int byte = prow*256 + ((((n*16+ln)*4)) ^ ((prow&7)<<4));
      *(float*)((char*)Ps + byte) = p;
    }
  }
  // intra = P @ Vs
  f32x4 acc[16];
  #pragma unroll
  for (int i=0;i<16;++i) acc[i] = fz;
  #pragma unroll
  for (int kk2=0;kk2<2;++kk2){
    int prow = w*16 + ln;
    int base = prow*256;
    int c0 = kk2*128 + g*32;
    int sw = (prow&7)<<4;
    f32x4 p0 = *(const f32x4*)((const char*)Ps + base + ((c0   )^sw));
    f32x4 p1 = *(const f32x4*)((const char*)Ps + base + ((c0+16)^sw));
    short8 ap;
    #pragma unroll
    for (int jj=0;jj<4;++jj){ ap[jj] = (short)f2bf(p0[jj]); ap[4+jj] = (short)f2bf(p1[jj]); }
    #pragma unroll
    for (int n2=0;n2<16;++n2){
      int vrow = n2*16 + ln;
      int byte = vrow*128 + ((kk2*64 + g*16) ^ ((vrow&7)<<4));
      short8 bv = *(const short8*)((const char*)Vt + byte);
      acc[n2] = __builtin_amdgcn_mfma_f32_16x16x32_bf16(ap, bv, acc[n2], 0,0,0);
    }
  }
  // scale intra by gamma^-64, add cross = Q @ State^T
  const float gi64 = exp2f(-64.f*lg2g);
  #pragma unroll
  for (int i=0;i<16;++i){ acc[i][0]*=gi64; acc[i][1]*=gi64; acc[i][2]*=gi64; acc[i][3]*=gi64; }
  const u16* st = States + (size_t)(c*12 + bh)*32768;
  #pragma unroll
  for (int kk=0;kk<4;++kk){
    #pragma unroll
    for (int n2=0;n2<16;++n2){
      short8 sb = *(const short8*)(st + (n2*16 + ln)*128 + kk*32 + g*8);
      acc[n2] = __builtin_amdgcn_mfma_f32_16x16x32_bf16(aq[kk], sb, acc[n2], 0,0,0);
    }
  }
  // epilogue
  float rf[4];
  #pragma unroll
  for (int r=0;r<4;++r){
    int a = w*16 + g*4 + r;
    int qi = q0 + a;
    float rs = (1.f - exp2f(lg2g*(float)(qi+1))) / omg;
    rf[r] = scale * exp2f(lg2g*(float)(a+1)) * rsqrtf(fmaxf(rs, 1e-6f));
  }
  float lsum=0.f, lsq=0.f;
  #pragma unroll
  for (int n2=0;n2<16;++n2){
    #pragma unroll
    for (int r=0;r<4;++r){
      float v = acc[n2][r]*rf[r];
      Of[(size_t)(b*2048 + q0 + w*16 + g*4 + r)*1536 + h*256 + n2*16 + ln] = v;
      lsum += v; lsq += v*v;
    }
  }
  #pragma unroll
  for (int o=32;o;o>>=1){ lsum += __shfl_xor(lsum,o,64); lsq += __shfl_xor(lsq,o,64); }
  if (l==0){ red[w*2]=lsum; red[w*2+1]=lsq; }
  __syncthreads();
  if (tid==0){
    partials[(c*12+bh)*2]   = red[0]+red[2]+red[4]+red[6];
    partials[(c*12+bh)*2+1] = red[1]+red[3]+red[5]+red[7];
  }
}

// ---------------- reduce 32 per-chunk partials per bh (12 blocks, no atomics) ----------------
__global__ __launch_bounds__(64)
void k_redstats(const float* __restrict__ partials, float* __restrict__ stats){
  int bh = blockIdx.x, l = threadIdx.x;
  float s=0.f, q=0.f;
  if (l < 32){ s = partials[(l*12+bh)*2]; q = partials[(l*12+bh)*2+1]; }
  #pragma unroll
  for (int o=16;o;o>>=1){ s += __shfl_xor(s,o,64); q += __shfl_xor(q,o,64); }
  if (l==0){ stats[bh*2] = s; stats[bh*2+1] = q; }
}

// ---------------- groupnorm + gate ----------------
__global__ void k_gatenorm(const float* __restrict__ Of, const u16* __restrict__ Gb,
                           const float* __restrict__ gnw, const float* __restrict__ gnb,
                           const float* __restrict__ stats, u16* __restrict__ Yb){
  size_t base = ((size_t)blockIdx.x*256 + threadIdx.x)*8;
  int m = (int)(base/1536);
  int c = (int)(base%1536);
  int bh = (m>>11)*6 + (c>>8);
  const float Ninv = 1.f/524288.f;
  float mean = stats[bh*2]*Ninv;
  float var = stats[bh*2+1]*Ninv - mean*mean;
  float rstd = rsqrtf(var + 1e-5f);
  #pragma unroll
  for (int jj=0;jj<8;++jj){
    float o = Of[base+jj];
    float nv = (o-mean)*rstd*gnw[c+jj] + gnb[c+jj];
    Yb[base+jj] = f2bf(nv * bf2f(Gb[base+jj]));
  }
}

// ---------------- launch ----------------
extern "C" void kernel_launch(void* const* d_in, const int* in_sizes, int n_in,
                              void* d_out, int out_size, void* d_ws, size_t ws_size,
                              hipStream_t stream)
{
  const float* x   = (const float*)d_in[0];
  const float* Wq  = (const float*)d_in[1];
  const float* Wk  = (const float*)d_in[2];
  const float* Wv  = (const float*)d_in[3];
  const float* Wg  = (const float*)d_in[4];
  const float* Wo  = (const float*)d_in[5];
  const float* gnw = (const float*)d_in[6];
  const float* gnb = (const float*)d_in[7];
  float* out = (float*)d_out;

  // Aliased workspace (live ranges):
  char* ws = (char*)d_ws;
  u16*   xb     = (u16*)  (ws + 0);          // [cvt -> gemm0]
  u16*   WT     = (u16*)  (ws + 6291456);    // [wtrans -> gemm0]
  u16*   Vraw   = (u16*)  (ws + 13369344);   // [gemm0 -> vtrans]
  float4* tab   = (float4*)(ws + 0);         // [xpostab -> xpos2] (over dead xb)
  u16*   KbT    = (u16*)  (ws + 6291456);    // [ktrans -> passA]  (over dead WT)
  u16*   States = (u16*)  (ws + 0);          // [scan -> passC]    (over dead xb/KbT/Vraw)
  u16*   Yb     = (u16*)  (ws + 0);          // [gatenorm -> gemm1](over dead States)
  u16*   Kr     = (u16*)  (ws + 25952256);   // [gemm0 -> passC]
  u16*   Qr     = (u16*)  (ws + 32243712);   // [gemm0 -> passC]
  u16*   Gb     = (u16*)  (ws + 38535168);   // [gemm0 -> gatenorm]
  u16*   WoT    = (u16*)  (ws + 51118080);   // [wtrans -> gemm1]
  u16*   VbTs   = (u16*)  (ws + 53477376);   // [vtrans -> passC]
  u16*   Zb     = (u16*)  (ws + 66060288);   // [passA -> scan]
  float* Of     = (float*)(ws + 66060288);   // [passC -> gatenorm] (over dead Zb)
  float* partials = (float*)(ws + 91226112); // [passC -> redstats]
  float* stats  = (float*)(ws + 91230208);   // [redstats -> gatenorm]

  k_cvt_x<<<3072, 256, 0, stream>>>(x, xb);
  k_wtrans_all<<<4608, dim3(32,8), 0, stream>>>(Wq, Wk, Wv, Wg, Wo, WT, WoT);
  k_gemm<0,128><<<dim3(32,36), 256, 0, stream>>>(xb, WT, 768, 4608, Qr, Kr, Vraw, Gb, (float*)nullptr);
  k_xpostab<<<512, 256, 0, stream>>>(tab);
  k_xpos2<<<1536, 256, 0, stream>>>(Qr, Kr, tab);
  k_vtrans<<<dim3(64,8,12), dim3(32,8), 0, stream>>>(Vraw, VbTs);
  k_ktrans<<<dim3(64,4,12), dim3(32,8), 0, stream>>>(Kr, KbT);
  k_passA<<<dim3(31,12), 256, 0, stream>>>(VbTs, KbT, Zb);
  k_scan<<<384, 256, 0, stream>>>(Zb, States);
  k_passC<<<dim3(32,12), 256, 0, stream>>>(Qr, Kr, VbTs, States, Of, partials);
  k_redstats<<<12, 64, 0, stream>>>(partials, stats);
  k_gatenorm<<<3072, 256, 0, stream>>>(Of, Gb, gnw, gnb, stats, Yb);
  k_gemm<1,64><<<dim3(64,6), 256, 0, stream>>>(Yb, WoT, 1536, 768,
                                            (u16*)nullptr,(u16*)nullptr,(u16*)nullptr,(u16*)nullptr, out);
}